// Round 1
// baseline (1017.420 us; speedup 1.0000x reference)
//
#include <hip/hip_runtime.h>

#define ETOT 524288
#define SGR  1024
#define NPG  64
#define EPG  512
#define NFD  32
#define EFD  16
#define HCD  64

__device__ __forceinline__ float elu_(float x){ return x>0.f ? x : (__expf(x)-1.f); }
__device__ __forceinline__ float sig_(float x){ return 1.f/(1.f+__expf(-x)); }
__device__ __forceinline__ float tanhf_(float x){ float e=__expf(2.f*x); return 1.f-2.f/(e+1.f); }
__device__ __forceinline__ float lrelu_(float x){ return x>0.f ? x : 0.2f*x; }

// Deterministic CSR build + per-dst mean edge_attr (self-loop fill).
// Called by all 512 threads; contains barriers.
__device__ void build_csr_la(int tid, int g, const int* ei, const float* ea,
                             int* s_edge, int* s_entry, int* s_off, int* s_deg,
                             float* s_la)
{
  const int base = g*NPG;
  const int* srcp = ei + (size_t)g*EPG;
  const int* dstp = ei + (size_t)ETOT + (size_t)g*EPG;
  for(int e=tid;e<EPG;e+=512)
    s_edge[e] = (srcp[e]-base) | ((dstp[e]-base)<<6);
  __syncthreads();
  if(tid<64){ int d=0;
    #pragma unroll 8
    for(int e=0;e<EPG;e++) d += (((s_edge[e]>>6)&63)==tid);
    s_deg[tid]=d; }
  __syncthreads();
  if(tid==0){ int a=0;
    for(int i=0;i<64;i++){ s_off[i]=a; a+=s_deg[i]; }
    s_off[64]=a; }
  __syncthreads();
  if(tid<64){ int pos=s_off[tid];
    for(int e=0;e<EPG;e++){ int en=s_edge[e];
      if(((en>>6)&63)==tid) s_entry[pos++] = (en&63) | (tid<<6) | (e<<12); } }
  __syncthreads();
  if(tid<256){ int n=tid>>2, f0=(tid&3)*4;
    float a0=0,a1=0,a2=0,a3=0;
    const int b=s_off[n], en=s_off[n+1];
    for(int p=b;p<en;p++){ int eid=s_entry[p]>>12;
      const float4 v = *(const float4*)(ea + ((size_t)g*EPG+(size_t)eid)*EFD + f0);
      a0+=v.x; a1+=v.y; a2+=v.z; a3+=v.w; }
    float inv = 1.f/fmaxf((float)(en-b),1.f);
    float4 r; r.x=a0*inv; r.y=a1*inv; r.z=a2*inv; r.w=a3*inv;
    *(float4*)(s_la + n*EFD + f0) = r; }
  __syncthreads();
}

// scores (576 = 512 edges + 64 self loops) + per-dst softmax; alpha left in s_sc.
__device__ void scores_softmax(int tid, int g, const float* ea,
   const int* s_entry, const int* s_off, const float* s_la,
   const float* s_We, const float* s_att, const float* s_xl, const float* s_xr,
   float* s_sc)
{
  for(int p=tid;p<576;p+=512){
    int src,dst; float eav[16];
    if(p<EPG){
      int en=s_entry[p]; src=en&63; dst=(en>>6)&63; int eid=en>>12;
      const float* epp = ea + ((size_t)g*EPG + (size_t)eid)*EFD;
      float4 v0=*(const float4*)(epp),   v1=*(const float4*)(epp+4);
      float4 v2=*(const float4*)(epp+8), v3=*(const float4*)(epp+12);
      eav[0]=v0.x;eav[1]=v0.y;eav[2]=v0.z;eav[3]=v0.w;
      eav[4]=v1.x;eav[5]=v1.y;eav[6]=v1.z;eav[7]=v1.w;
      eav[8]=v2.x;eav[9]=v2.y;eav[10]=v2.z;eav[11]=v2.w;
      eav[12]=v3.x;eav[13]=v3.y;eav[14]=v3.z;eav[15]=v3.w;
    } else {
      int n=p-EPG; src=n; dst=n;
      const float* epp = s_la + n*EFD;
      float4 v0=*(const float4*)(epp),   v1=*(const float4*)(epp+4);
      float4 v2=*(const float4*)(epp+8), v3=*(const float4*)(epp+12);
      eav[0]=v0.x;eav[1]=v0.y;eav[2]=v0.z;eav[3]=v0.w;
      eav[4]=v1.x;eav[5]=v1.y;eav[6]=v1.z;eav[7]=v1.w;
      eav[8]=v2.x;eav[9]=v2.y;eav[10]=v2.z;eav[11]=v2.w;
      eav[12]=v3.x;eav[13]=v3.y;eav[14]=v3.z;eav[15]=v3.w;
    }
    float score=0.f;
    #pragma unroll 4
    for(int cq=0;cq<16;cq++){
      float e0=0.f,e1=0.f,e2=0.f,e3=0.f;
      #pragma unroll
      for(int f=0;f<16;f++){
        const float4 wv=*(const float4*)(s_We + f*64 + cq*4);
        e0+=eav[f]*wv.x; e1+=eav[f]*wv.y; e2+=eav[f]*wv.z; e3+=eav[f]*wv.w;
      }
      const float4 xlv=*(const float4*)(s_xl + src*64 + ((cq^(src&15))<<2));
      const float4 xrv=*(const float4*)(s_xr + dst*64 + ((cq^(dst&15))<<2));
      const float4 av =*(const float4*)(s_att + cq*4);
      float m0=lrelu_(xlv.x+xrv.x+e0), m1=lrelu_(xlv.y+xrv.y+e1);
      float m2=lrelu_(xlv.z+xrv.z+e2), m3=lrelu_(xlv.w+xrv.w+e3);
      score += m0*av.x+m1*av.y+m2*av.z+m3*av.w;
    }
    s_sc[p]=score;
  }
  __syncthreads();
  if(tid<64){
    const int b=s_off[tid], e=s_off[tid+1];
    float mx=s_sc[EPG+tid];
    for(int p=b;p<e;p++) mx=fmaxf(mx,s_sc[p]);
    float v=__expf(s_sc[EPG+tid]-mx); float den=v; s_sc[EPG+tid]=v;
    for(int p=b;p<e;p++){ float w=__expf(s_sc[p]-mx); s_sc[p]=w; den+=w; }
    const float inv=1.f/(den+1e-16f);
    s_sc[EPG+tid]*=inv;
    for(int p=b;p<e;p++) s_sc[p]*=inv;
  }
  __syncthreads();
}

__global__ __launch_bounds__(512,4) void gat1_k(
    const float* __restrict__ x, const int* __restrict__ ei,
    const float* __restrict__ ea, const float* __restrict__ Wl,
    const float* __restrict__ bl, const float* __restrict__ Wr,
    const float* __restrict__ br, const float* __restrict__ We,
    const float* __restrict__ att, const float* __restrict__ bias,
    float* __restrict__ h1)
{
  const int g = blockIdx.x, tid = threadIdx.x;
  const int base = g*NPG;

  __shared__ __align__(16) float s_x[NPG*36];
  __shared__ __align__(16) float s_xl[NPG*64];
  __shared__ __align__(16) float s_xr[NPG*64];
  __shared__ __align__(16) float s_W[2*32*64];
  __shared__ __align__(16) float s_We[16*64];
  __shared__ __align__(16) float s_att[64];
  __shared__ __align__(16) float s_la[NPG*EFD];
  __shared__ float s_sc[576];
  __shared__ int   s_edge[EPG];
  __shared__ int   s_entry[EPG];
  __shared__ int   s_off[65];
  __shared__ int   s_deg[64];

  // stage x tile [64][32] (padded stride 36)
  { int n=tid>>3, kq=tid&7;
    float4 v = *(const float4*)(x + (size_t)(base+n)*NFD + kq*4);
    *(float4*)(s_x + n*36 + kq*4) = v; }

  build_csr_la(tid, g, ei, ea, s_edge, s_entry, s_off, s_deg, s_la);

  for(int h=0;h<3;h++){
    // stage weight slices for this head
    { int k=tid>>4, c0=(tid&15)*4;
      *(float4*)(s_W + k*64 + c0)        = *(const float4*)(Wl + (size_t)k*192 + h*64 + c0);
      *(float4*)(s_W + 2048 + k*64 + c0) = *(const float4*)(Wr + (size_t)k*192 + h*64 + c0); }
    if(tid<256){ int f=tid>>4, c0=(tid&15)*4;
      *(float4*)(s_We + f*64 + c0) = *(const float4*)(We + (size_t)f*192 + h*64 + c0); }
    if(tid<16) *(float4*)(s_att + tid*4) = *(const float4*)(att + h*64 + tid*4);
    __syncthreads();

    // GEMM: xl = x@Wl_h + bl_h ; xr = x@Wr_h + br_h  (64x32 @ 32x64)
    { const int cg=tid&15, ng=tid>>4, n0=ng*2, c0=cg*4;
      const float4 blv=*(const float4*)(bl + h*64 + c0);
      const float4 brv=*(const float4*)(br + h*64 + c0);
      float accl[2][4]={{blv.x,blv.y,blv.z,blv.w},{blv.x,blv.y,blv.z,blv.w}};
      float accr[2][4]={{brv.x,brv.y,brv.z,brv.w},{brv.x,brv.y,brv.z,brv.w}};
      #pragma unroll
      for(int kq=0;kq<8;kq++){
        float xs0[4], xs1[4];
        { float4 v=*(const float4*)(s_x + n0*36 + kq*4);     xs0[0]=v.x;xs0[1]=v.y;xs0[2]=v.z;xs0[3]=v.w; }
        { float4 v=*(const float4*)(s_x + (n0+1)*36 + kq*4); xs1[0]=v.x;xs1[1]=v.y;xs1[2]=v.z;xs1[3]=v.w; }
        #pragma unroll
        for(int f=0;f<4;f++){
          const float4 wl=*(const float4*)(s_W + (kq*4+f)*64 + c0);
          const float4 wr=*(const float4*)(s_W + 2048 + (kq*4+f)*64 + c0);
          accl[0][0]+=xs0[f]*wl.x; accl[0][1]+=xs0[f]*wl.y; accl[0][2]+=xs0[f]*wl.z; accl[0][3]+=xs0[f]*wl.w;
          accl[1][0]+=xs1[f]*wl.x; accl[1][1]+=xs1[f]*wl.y; accl[1][2]+=xs1[f]*wl.z; accl[1][3]+=xs1[f]*wl.w;
          accr[0][0]+=xs0[f]*wr.x; accr[0][1]+=xs0[f]*wr.y; accr[0][2]+=xs0[f]*wr.z; accr[0][3]+=xs0[f]*wr.w;
          accr[1][0]+=xs1[f]*wr.x; accr[1][1]+=xs1[f]*wr.y; accr[1][2]+=xs1[f]*wr.z; accr[1][3]+=xs1[f]*wr.w;
        }
      }
      #pragma unroll
      for(int i=0;i<2;i++){
        const int n=n0+i, sq=((cg^(n&15))<<2);
        float4 vl; vl.x=accl[i][0]; vl.y=accl[i][1]; vl.z=accl[i][2]; vl.w=accl[i][3];
        float4 vr; vr.x=accr[i][0]; vr.y=accr[i][1]; vr.z=accr[i][2]; vr.w=accr[i][3];
        *(float4*)(s_xl + n*64 + sq)=vl;
        *(float4*)(s_xr + n*64 + sq)=vr;
      }
    }
    __syncthreads();

    scores_softmax(tid, g, ea, s_entry, s_off, s_la, s_We, s_att, s_xl, s_xr, s_sc);

    // aggregate alpha * xl[src] per (dst, 8-channel slice) + bias + ELU -> h1
    { const int n=tid>>3, c0a=(tid&7)*8;
      float acc[8]={0.f,0.f,0.f,0.f,0.f,0.f,0.f,0.f};
      const int b=s_off[n], e=s_off[n+1];
      for(int p=b;p<e;p++){
        const int en=s_entry[p], src=en&63;
        const float a=s_sc[p];
        #pragma unroll
        for(int qq=0;qq<2;qq++){
          const int cq=(c0a>>2)+qq;
          const float4 xv=*(const float4*)(s_xl + src*64 + ((cq^(src&15))<<2));
          acc[qq*4+0]+=a*xv.x; acc[qq*4+1]+=a*xv.y; acc[qq*4+2]+=a*xv.z; acc[qq*4+3]+=a*xv.w;
        }
      }
      { const float a=s_sc[EPG+n];
        #pragma unroll
        for(int qq=0;qq<2;qq++){
          const int cq=(c0a>>2)+qq;
          const float4 xv=*(const float4*)(s_xl + n*64 + ((cq^(n&15))<<2));
          acc[qq*4+0]+=a*xv.x; acc[qq*4+1]+=a*xv.y; acc[qq*4+2]+=a*xv.z; acc[qq*4+3]+=a*xv.w;
        } }
      float* op = h1 + (size_t)(base+n)*192 + h*64 + c0a;
      #pragma unroll
      for(int qq=0;qq<2;qq++){
        const float4 bv=*(const float4*)(bias + h*64 + c0a + qq*4);
        float4 r; r.x=elu_(acc[qq*4+0]+bv.x); r.y=elu_(acc[qq*4+1]+bv.y);
                  r.z=elu_(acc[qq*4+2]+bv.z); r.w=elu_(acc[qq*4+3]+bv.w);
        *(float4*)(op + qq*4)=r;
      }
    }
    __syncthreads();
  }
}

__global__ __launch_bounds__(512,4) void gat2_k(
    const float* __restrict__ h1, const int* __restrict__ ei,
    const float* __restrict__ ea, const float* __restrict__ Wl,
    const float* __restrict__ bl, const float* __restrict__ Wr,
    const float* __restrict__ br, const float* __restrict__ We,
    const float* __restrict__ att, const float* __restrict__ bias,
    const float* __restrict__ Wih, const float* __restrict__ bih,
    const float* __restrict__ bhh, float* __restrict__ xproj)
{
  const int g = blockIdx.x, tid = threadIdx.x;
  const int base = g*NPG;

  __shared__ __align__(16) float s_hx[NPG*36];
  __shared__ __align__(16) float s_xl[NPG*64];
  __shared__ __align__(16) float s_xr[NPG*64];
  __shared__ __align__(16) float s_W[2*32*64];   // also reused as s_out (64x64)
  __shared__ __align__(16) float s_We[16*64];
  __shared__ __align__(16) float s_att[64];
  __shared__ __align__(16) float s_la[NPG*EFD];
  __shared__ float s_sc[576];
  __shared__ float s_pool[64];
  __shared__ int   s_edge[EPG];
  __shared__ int   s_entry[EPG];
  __shared__ int   s_off[65];
  __shared__ int   s_deg[64];
  float* s_out = s_W;

  build_csr_la(tid, g, ei, ea, s_edge, s_entry, s_off, s_deg, s_la);

  // GEMM: xl/xr = h1 @ Wl2/Wr2 + b  (64x192 @ 192x64, 6 K-chunks of 32)
  const int cg=tid&15, ng=tid>>4, n0=ng*2, gc0=cg*4;
  float accl[2][4], accr[2][4];
  { const float4 blv=*(const float4*)(bl + gc0);
    const float4 brv=*(const float4*)(br + gc0);
    #pragma unroll
    for(int i=0;i<2;i++){
      accl[i][0]=blv.x; accl[i][1]=blv.y; accl[i][2]=blv.z; accl[i][3]=blv.w;
      accr[i][0]=brv.x; accr[i][1]=brv.y; accr[i][2]=brv.z; accr[i][3]=brv.w; } }
  for(int kc=0;kc<6;kc++){
    { int n=tid>>3, kq=tid&7;
      *(float4*)(s_hx + n*36 + kq*4) = *(const float4*)(h1 + (size_t)(base+n)*192 + kc*32 + kq*4); }
    { int k=tid>>4, cc=(tid&15)*4;
      *(float4*)(s_W + k*64 + cc)        = *(const float4*)(Wl + (size_t)(kc*32+k)*64 + cc);
      *(float4*)(s_W + 2048 + k*64 + cc) = *(const float4*)(Wr + (size_t)(kc*32+k)*64 + cc); }
    __syncthreads();
    #pragma unroll
    for(int kq=0;kq<8;kq++){
      float xs0[4], xs1[4];
      { float4 v=*(const float4*)(s_hx + n0*36 + kq*4);     xs0[0]=v.x;xs0[1]=v.y;xs0[2]=v.z;xs0[3]=v.w; }
      { float4 v=*(const float4*)(s_hx + (n0+1)*36 + kq*4); xs1[0]=v.x;xs1[1]=v.y;xs1[2]=v.z;xs1[3]=v.w; }
      #pragma unroll
      for(int f=0;f<4;f++){
        const float4 wl=*(const float4*)(s_W + (kq*4+f)*64 + gc0);
        const float4 wr=*(const float4*)(s_W + 2048 + (kq*4+f)*64 + gc0);
        accl[0][0]+=xs0[f]*wl.x; accl[0][1]+=xs0[f]*wl.y; accl[0][2]+=xs0[f]*wl.z; accl[0][3]+=xs0[f]*wl.w;
        accl[1][0]+=xs1[f]*wl.x; accl[1][1]+=xs1[f]*wl.y; accl[1][2]+=xs1[f]*wl.z; accl[1][3]+=xs1[f]*wl.w;
        accr[0][0]+=xs0[f]*wr.x; accr[0][1]+=xs0[f]*wr.y; accr[0][2]+=xs0[f]*wr.z; accr[0][3]+=xs0[f]*wr.w;
        accr[1][0]+=xs1[f]*wr.x; accr[1][1]+=xs1[f]*wr.y; accr[1][2]+=xs1[f]*wr.z; accr[1][3]+=xs1[f]*wr.w;
      }
    }
    __syncthreads();
  }
  // write xl/xr (swizzled) and stage We2/att2
  #pragma unroll
  for(int i=0;i<2;i++){
    const int n=n0+i, sq=((cg^(n&15))<<2);
    float4 vl; vl.x=accl[i][0]; vl.y=accl[i][1]; vl.z=accl[i][2]; vl.w=accl[i][3];
    float4 vr; vr.x=accr[i][0]; vr.y=accr[i][1]; vr.z=accr[i][2]; vr.w=accr[i][3];
    *(float4*)(s_xl + n*64 + sq)=vl;
    *(float4*)(s_xr + n*64 + sq)=vr;
  }
  if(tid<256){ int f=tid>>4, cc=(tid&15)*4;
    *(float4*)(s_We + f*64 + cc) = *(const float4*)(We + (size_t)f*64 + cc); }
  if(tid<16) *(float4*)(s_att + tid*4) = *(const float4*)(att + tid*4);
  __syncthreads();

  scores_softmax(tid, g, ea, s_entry, s_off, s_la, s_We, s_att, s_xl, s_xr, s_sc);

  // aggregate + bias + ELU into s_out (aliases s_W; GEMM done)
  { const int n=tid>>3, c0a=(tid&7)*8;
    float acc[8]={0.f,0.f,0.f,0.f,0.f,0.f,0.f,0.f};
    const int b=s_off[n], e=s_off[n+1];
    for(int p=b;p<e;p++){
      const int en=s_entry[p], src=en&63;
      const float a=s_sc[p];
      #pragma unroll
      for(int qq=0;qq<2;qq++){
        const int cq=(c0a>>2)+qq;
        const float4 xv=*(const float4*)(s_xl + src*64 + ((cq^(src&15))<<2));
        acc[qq*4+0]+=a*xv.x; acc[qq*4+1]+=a*xv.y; acc[qq*4+2]+=a*xv.z; acc[qq*4+3]+=a*xv.w;
      }
    }
    { const float a=s_sc[EPG+n];
      #pragma unroll
      for(int qq=0;qq<2;qq++){
        const int cq=(c0a>>2)+qq;
        const float4 xv=*(const float4*)(s_xl + n*64 + ((cq^(n&15))<<2));
        acc[qq*4+0]+=a*xv.x; acc[qq*4+1]+=a*xv.y; acc[qq*4+2]+=a*xv.z; acc[qq*4+3]+=a*xv.w;
      } }
    #pragma unroll
    for(int qq=0;qq<2;qq++){
      const float4 bv=*(const float4*)(bias + c0a + qq*4);
      float4 r; r.x=elu_(acc[qq*4+0]+bv.x); r.y=elu_(acc[qq*4+1]+bv.y);
                r.z=elu_(acc[qq*4+2]+bv.z); r.w=elu_(acc[qq*4+3]+bv.w);
      *(float4*)(s_out + n*64 + c0a + qq*4)=r;
    }
  }
  __syncthreads();
  // mean-pool over the 64 nodes
  if(tid<64){ float s=0.f;
    #pragma unroll 8
    for(int n2=0;n2<64;n2++) s += s_out[n2*64+tid];
    s_pool[tid]=s*(1.f/64.f); }
  __syncthreads();
  // LSTM input projection for this timestep: xproj[g][r] = bih[r]+bhh[r]+Wih[r]·pooled
  if(tid<256){
    float a=bih[tid]+bhh[tid];
    #pragma unroll
    for(int kq=0;kq<16;kq++){
      const float4 w=*(const float4*)(Wih + (size_t)tid*64 + kq*4);
      a += w.x*s_pool[kq*4+0] + w.y*s_pool[kq*4+1] + w.z*s_pool[kq*4+2] + w.w*s_pool[kq*4+3];
    }
    xproj[(size_t)g*256 + tid]=a;
  }
}

__global__ __launch_bounds__(256,1) void lstm_k(
    const float* __restrict__ xproj, const float* __restrict__ Whh,
    const float* __restrict__ W1, const float* __restrict__ b1,
    const float* __restrict__ W2, const float* __restrict__ b2,
    float* __restrict__ out)
{
  const int tid=threadIdx.x, l=tid>>2, q=tid&3;
  __shared__ __align__(16) float s_h[64];
  __shared__ float s_y[32];
  // thread (l,q): k-quarter q of Whh rows {l, 64+l, 128+l, 192+l}
  float w[4][16];
  #pragma unroll
  for(int m=0;m<4;m++){
    const float* wp = Whh + (size_t)(m*64+l)*64 + q*16;
    #pragma unroll
    for(int j=0;j<4;j++){
      const float4 v=*(const float4*)(wp + j*4);
      w[m][j*4]=v.x; w[m][j*4+1]=v.y; w[m][j*4+2]=v.z; w[m][j*4+3]=v.w;
    }
  }
  float c=0.f;
  float xp0=0.f,xp1=0.f,xp2=0.f,xp3=0.f;
  if(q==0){ xp0=xproj[l]; xp1=xproj[64+l]; xp2=xproj[128+l]; xp3=xproj[192+l]; }
  if(tid<64) s_h[tid]=0.f;
  __syncthreads();
  for(int t=0;t<1024;t++){
    float hb[16];
    #pragma unroll
    for(int j=0;j<4;j++){
      const float4 v=*(const float4*)(s_h + q*16 + j*4);
      hb[j*4]=v.x; hb[j*4+1]=v.y; hb[j*4+2]=v.z; hb[j*4+3]=v.w;
    }
    float a0=0.f,a1=0.f,a2=0.f,a3=0.f;
    #pragma unroll
    for(int k=0;k<16;k++){
      a0+=w[0][k]*hb[k]; a1+=w[1][k]*hb[k]; a2+=w[2][k]*hb[k]; a3+=w[3][k]*hb[k];
    }
    a0 += __shfl_xor(a0,1); a0 += __shfl_xor(a0,2);
    a1 += __shfl_xor(a1,1); a1 += __shfl_xor(a1,2);
    a2 += __shfl_xor(a2,1); a2 += __shfl_xor(a2,2);
    a3 += __shfl_xor(a3,1); a3 += __shfl_xor(a3,2);
    if(q==0){
      const float gi=a0+xp0, gf=a1+xp1, gg=a2+xp2, go=a3+xp3;
      if(t<1023){
        const float* xpp = xproj + (size_t)(t+1)*256;
        xp0=xpp[l]; xp1=xpp[64+l]; xp2=xpp[128+l]; xp3=xpp[192+l];
      }
      c = sig_(gf)*c + sig_(gi)*tanhf_(gg);
      s_h[l] = sig_(go)*tanhf_(c);
    }
    __syncthreads();
  }
  // MLP head: relu(h@W1+b1)@W2+b2
  if(tid<32){
    float a=b1[tid];
    #pragma unroll 8
    for(int k=0;k<64;k++) a += s_h[k]*W1[k*32+tid];
    s_y[tid]=fmaxf(a,0.f);
  }
  __syncthreads();
  if(tid==0){
    float a=b2[0];
    #pragma unroll
    for(int j=0;j<32;j++) a += s_y[j]*W2[j];
    out[0]=a;
  }
}

extern "C" void kernel_launch(void* const* d_in, const int* in_sizes, int n_in,
                              void* d_out, int out_size, void* d_ws, size_t ws_size,
                              hipStream_t stream) {
  (void)in_sizes; (void)n_in; (void)out_size; (void)ws_size;
  const float* x    = (const float*)d_in[0];
  const int*   ei   = (const int*)d_in[1];
  const float* ea   = (const float*)d_in[2];
  const float* Wl1  = (const float*)d_in[4];
  const float* bl1  = (const float*)d_in[5];
  const float* Wr1  = (const float*)d_in[6];
  const float* br1  = (const float*)d_in[7];
  const float* We1  = (const float*)d_in[8];
  const float* att1 = (const float*)d_in[9];
  const float* bias1= (const float*)d_in[10];
  const float* Wl2  = (const float*)d_in[11];
  const float* bl2  = (const float*)d_in[12];
  const float* Wr2  = (const float*)d_in[13];
  const float* br2  = (const float*)d_in[14];
  const float* We2  = (const float*)d_in[15];
  const float* att2 = (const float*)d_in[16];
  const float* bias2= (const float*)d_in[17];
  const float* Wih  = (const float*)d_in[18];
  const float* Whh  = (const float*)d_in[19];
  const float* bih  = (const float*)d_in[20];
  const float* bhh  = (const float*)d_in[21];
  const float* W1   = (const float*)d_in[22];
  const float* b1   = (const float*)d_in[23];
  const float* W2   = (const float*)d_in[24];
  const float* b2   = (const float*)d_in[25];

  float* h1w = (float*)d_ws;                                  // 65536*192*4 = 50331648 B
  float* xpw = (float*)((char*)d_ws + (size_t)50331648);      // 1024*256*4  = 1048576 B
  float* outp = (float*)d_out;

  gat1_k<<<dim3(SGR), dim3(512), 0, stream>>>(x, ei, ea, Wl1, bl1, Wr1, br1, We1, att1, bias1, h1w);
  gat2_k<<<dim3(SGR), dim3(512), 0, stream>>>(h1w, ei, ea, Wl2, bl2, Wr2, br2, We2, att2, bias2,
                                              Wih, bih, bhh, xpw);
  lstm_k<<<dim3(1), dim3(256), 0, stream>>>(xpw, Whh, W1, b1, W2, b2, outp);
}

// Round 2
// 896.194 us; speedup vs baseline: 1.1353x; 1.1353x over previous
//
#include <hip/hip_runtime.h>

#define ETOT 524288
#define SGR  1024
#define NPG  64
#define EPG  512
#define NFD  32
#define EFD  16
#define HCD  64

__device__ __forceinline__ float elu_(float x){ return x>0.f ? x : (__expf(x)-1.f); }
__device__ __forceinline__ float sig_(float x){ return 1.f/(1.f+__expf(-x)); }
__device__ __forceinline__ float tanhf_(float x){ float e=__expf(2.f*x); return 1.f-2.f/(e+1.f); }
__device__ __forceinline__ float lrelu_(float x){ return x>0.f ? x : 0.2f*x; }

// sum over the 4 lanes of a quad, result in all 4 lanes — VALU DPP, no LDS pipe
__device__ __forceinline__ float quad_add(float v){
  int t = __builtin_amdgcn_update_dpp(0, __float_as_int(v), 0xB1, 0xF, 0xF, true); // [1,0,3,2]
  v += __int_as_float(t);
  t = __builtin_amdgcn_update_dpp(0, __float_as_int(v), 0x4E, 0xF, 0xF, true);     // [2,3,0,1]
  return v + __int_as_float(t);
}

// Deterministic CSR build + per-dst mean edge_attr (self-loop fill).
// Called by all 512 threads; contains barriers.
__device__ void build_csr_la(int tid, int g, const int* ei, const float* ea,
                             int* s_edge, int* s_entry, int* s_off, int* s_deg,
                             float* s_la)
{
  const int base = g*NPG;
  const int* srcp = ei + (size_t)g*EPG;
  const int* dstp = ei + (size_t)ETOT + (size_t)g*EPG;
  for(int e=tid;e<EPG;e+=512)
    s_edge[e] = (srcp[e]-base) | ((dstp[e]-base)<<6);
  __syncthreads();
  if(tid<64){ int d=0;
    #pragma unroll 8
    for(int e=0;e<EPG;e++) d += (((s_edge[e]>>6)&63)==tid);
    s_deg[tid]=d; }
  __syncthreads();
  if(tid==0){ int a=0;
    for(int i=0;i<64;i++){ s_off[i]=a; a+=s_deg[i]; }
    s_off[64]=a; }
  __syncthreads();
  if(tid<64){ int pos=s_off[tid];
    for(int e=0;e<EPG;e++){ int en=s_edge[e];
      if(((en>>6)&63)==tid) s_entry[pos++] = (en&63) | (tid<<6) | (e<<12); } }
  __syncthreads();
  if(tid<256){ int n=tid>>2, f0=(tid&3)*4;
    float a0=0,a1=0,a2=0,a3=0;
    const int b=s_off[n], en=s_off[n+1];
    for(int p=b;p<en;p++){ int eid=s_entry[p]>>12;
      const float4 v = *(const float4*)(ea + ((size_t)g*EPG+(size_t)eid)*EFD + f0);
      a0+=v.x; a1+=v.y; a2+=v.z; a3+=v.w; }
    float inv = 1.f/fmaxf((float)(en-b),1.f);
    float4 r; r.x=a0*inv; r.y=a1*inv; r.z=a2*inv; r.w=a3*inv;
    *(float4*)(s_la + n*EFD + f0) = r; }
  __syncthreads();
}

// scores (576 = 512 edges + 64 self loops) + per-dst softmax; alpha left in s_sc.
__device__ void scores_softmax(int tid, int g, const float* ea,
   const int* s_entry, const int* s_off, const float* s_la,
   const float* s_We, const float* s_att, const float* s_xl, const float* s_xr,
   float* s_sc)
{
  for(int p=tid;p<576;p+=512){
    int src,dst; float eav[16];
    if(p<EPG){
      int en=s_entry[p]; src=en&63; dst=(en>>6)&63; int eid=en>>12;
      const float* epp = ea + ((size_t)g*EPG + (size_t)eid)*EFD;
      float4 v0=*(const float4*)(epp),   v1=*(const float4*)(epp+4);
      float4 v2=*(const float4*)(epp+8), v3=*(const float4*)(epp+12);
      eav[0]=v0.x;eav[1]=v0.y;eav[2]=v0.z;eav[3]=v0.w;
      eav[4]=v1.x;eav[5]=v1.y;eav[6]=v1.z;eav[7]=v1.w;
      eav[8]=v2.x;eav[9]=v2.y;eav[10]=v2.z;eav[11]=v2.w;
      eav[12]=v3.x;eav[13]=v3.y;eav[14]=v3.z;eav[15]=v3.w;
    } else {
      int n=p-EPG; src=n; dst=n;
      const float* epp = s_la + n*EFD;
      float4 v0=*(const float4*)(epp),   v1=*(const float4*)(epp+4);
      float4 v2=*(const float4*)(epp+8), v3=*(const float4*)(epp+12);
      eav[0]=v0.x;eav[1]=v0.y;eav[2]=v0.z;eav[3]=v0.w;
      eav[4]=v1.x;eav[5]=v1.y;eav[6]=v1.z;eav[7]=v1.w;
      eav[8]=v2.x;eav[9]=v2.y;eav[10]=v2.z;eav[11]=v2.w;
      eav[12]=v3.x;eav[13]=v3.y;eav[14]=v3.z;eav[15]=v3.w;
    }
    float score=0.f;
    #pragma unroll 4
    for(int cq=0;cq<16;cq++){
      float e0=0.f,e1=0.f,e2=0.f,e3=0.f;
      #pragma unroll
      for(int f=0;f<16;f++){
        const float4 wv=*(const float4*)(s_We + f*64 + cq*4);
        e0+=eav[f]*wv.x; e1+=eav[f]*wv.y; e2+=eav[f]*wv.z; e3+=eav[f]*wv.w;
      }
      const float4 xlv=*(const float4*)(s_xl + src*64 + ((cq^(src&15))<<2));
      const float4 xrv=*(const float4*)(s_xr + dst*64 + ((cq^(dst&15))<<2));
      const float4 av =*(const float4*)(s_att + cq*4);
      float m0=lrelu_(xlv.x+xrv.x+e0), m1=lrelu_(xlv.y+xrv.y+e1);
      float m2=lrelu_(xlv.z+xrv.z+e2), m3=lrelu_(xlv.w+xrv.w+e3);
      score += m0*av.x+m1*av.y+m2*av.z+m3*av.w;
    }
    s_sc[p]=score;
  }
  __syncthreads();
  if(tid<64){
    const int b=s_off[tid], e=s_off[tid+1];
    float mx=s_sc[EPG+tid];
    for(int p=b;p<e;p++) mx=fmaxf(mx,s_sc[p]);
    float v=__expf(s_sc[EPG+tid]-mx); float den=v; s_sc[EPG+tid]=v;
    for(int p=b;p<e;p++){ float w=__expf(s_sc[p]-mx); s_sc[p]=w; den+=w; }
    const float inv=1.f/(den+1e-16f);
    s_sc[EPG+tid]*=inv;
    for(int p=b;p<e;p++) s_sc[p]*=inv;
  }
  __syncthreads();
}

__global__ __launch_bounds__(512,4) void gat1_k(
    const float* __restrict__ x, const int* __restrict__ ei,
    const float* __restrict__ ea, const float* __restrict__ Wl,
    const float* __restrict__ bl, const float* __restrict__ Wr,
    const float* __restrict__ br, const float* __restrict__ We,
    const float* __restrict__ att, const float* __restrict__ bias,
    float* __restrict__ h1)
{
  const int g = blockIdx.x, tid = threadIdx.x;
  const int base = g*NPG;

  __shared__ __align__(16) float s_x[NPG*36];
  __shared__ __align__(16) float s_xl[NPG*64];
  __shared__ __align__(16) float s_xr[NPG*64];
  __shared__ __align__(16) float s_W[2*32*64];
  __shared__ __align__(16) float s_We[16*64];
  __shared__ __align__(16) float s_att[64];
  __shared__ __align__(16) float s_la[NPG*EFD];
  __shared__ float s_sc[576];
  __shared__ int   s_edge[EPG];
  __shared__ int   s_entry[EPG];
  __shared__ int   s_off[65];
  __shared__ int   s_deg[64];

  // stage x tile [64][32] (padded stride 36)
  { int n=tid>>3, kq=tid&7;
    float4 v = *(const float4*)(x + (size_t)(base+n)*NFD + kq*4);
    *(float4*)(s_x + n*36 + kq*4) = v; }

  build_csr_la(tid, g, ei, ea, s_edge, s_entry, s_off, s_deg, s_la);

  for(int h=0;h<3;h++){
    // stage weight slices for this head
    { int k=tid>>4, c0=(tid&15)*4;
      *(float4*)(s_W + k*64 + c0)        = *(const float4*)(Wl + (size_t)k*192 + h*64 + c0);
      *(float4*)(s_W + 2048 + k*64 + c0) = *(const float4*)(Wr + (size_t)k*192 + h*64 + c0); }
    if(tid<256){ int f=tid>>4, c0=(tid&15)*4;
      *(float4*)(s_We + f*64 + c0) = *(const float4*)(We + (size_t)f*192 + h*64 + c0); }
    if(tid<16) *(float4*)(s_att + tid*4) = *(const float4*)(att + h*64 + tid*4);
    __syncthreads();

    // GEMM: xl = x@Wl_h + bl_h ; xr = x@Wr_h + br_h  (64x32 @ 32x64)
    { const int cg=tid&15, ng=tid>>4, n0=ng*2, c0=cg*4;
      const float4 blv=*(const float4*)(bl + h*64 + c0);
      const float4 brv=*(const float4*)(br + h*64 + c0);
      float accl[2][4]={{blv.x,blv.y,blv.z,blv.w},{blv.x,blv.y,blv.z,blv.w}};
      float accr[2][4]={{brv.x,brv.y,brv.z,brv.w},{brv.x,brv.y,brv.z,brv.w}};
      #pragma unroll
      for(int kq=0;kq<8;kq++){
        float xs0[4], xs1[4];
        { float4 v=*(const float4*)(s_x + n0*36 + kq*4);     xs0[0]=v.x;xs0[1]=v.y;xs0[2]=v.z;xs0[3]=v.w; }
        { float4 v=*(const float4*)(s_x + (n0+1)*36 + kq*4); xs1[0]=v.x;xs1[1]=v.y;xs1[2]=v.z;xs1[3]=v.w; }
        #pragma unroll
        for(int f=0;f<4;f++){
          const float4 wl=*(const float4*)(s_W + (kq*4+f)*64 + c0);
          const float4 wr=*(const float4*)(s_W + 2048 + (kq*4+f)*64 + c0);
          accl[0][0]+=xs0[f]*wl.x; accl[0][1]+=xs0[f]*wl.y; accl[0][2]+=xs0[f]*wl.z; accl[0][3]+=xs0[f]*wl.w;
          accl[1][0]+=xs1[f]*wl.x; accl[1][1]+=xs1[f]*wl.y; accl[1][2]+=xs1[f]*wl.z; accl[1][3]+=xs1[f]*wl.w;
          accr[0][0]+=xs0[f]*wr.x; accr[0][1]+=xs0[f]*wr.y; accr[0][2]+=xs0[f]*wr.z; accr[0][3]+=xs0[f]*wr.w;
          accr[1][0]+=xs1[f]*wr.x; accr[1][1]+=xs1[f]*wr.y; accr[1][2]+=xs1[f]*wr.z; accr[1][3]+=xs1[f]*wr.w;
        }
      }
      #pragma unroll
      for(int i=0;i<2;i++){
        const int n=n0+i, sq=((cg^(n&15))<<2);
        float4 vl; vl.x=accl[i][0]; vl.y=accl[i][1]; vl.z=accl[i][2]; vl.w=accl[i][3];
        float4 vr; vr.x=accr[i][0]; vr.y=accr[i][1]; vr.z=accr[i][2]; vr.w=accr[i][3];
        *(float4*)(s_xl + n*64 + sq)=vl;
        *(float4*)(s_xr + n*64 + sq)=vr;
      }
    }
    __syncthreads();

    scores_softmax(tid, g, ea, s_entry, s_off, s_la, s_We, s_att, s_xl, s_xr, s_sc);

    // aggregate alpha * xl[src] per (dst, 8-channel slice) + bias + ELU -> h1
    { const int n=tid>>3, c0a=(tid&7)*8;
      float acc[8]={0.f,0.f,0.f,0.f,0.f,0.f,0.f,0.f};
      const int b=s_off[n], e=s_off[n+1];
      for(int p=b;p<e;p++){
        const int en=s_entry[p], src=en&63;
        const float a=s_sc[p];
        #pragma unroll
        for(int qq=0;qq<2;qq++){
          const int cq=(c0a>>2)+qq;
          const float4 xv=*(const float4*)(s_xl + src*64 + ((cq^(src&15))<<2));
          acc[qq*4+0]+=a*xv.x; acc[qq*4+1]+=a*xv.y; acc[qq*4+2]+=a*xv.z; acc[qq*4+3]+=a*xv.w;
        }
      }
      { const float a=s_sc[EPG+n];
        #pragma unroll
        for(int qq=0;qq<2;qq++){
          const int cq=(c0a>>2)+qq;
          const float4 xv=*(const float4*)(s_xl + n*64 + ((cq^(n&15))<<2));
          acc[qq*4+0]+=a*xv.x; acc[qq*4+1]+=a*xv.y; acc[qq*4+2]+=a*xv.z; acc[qq*4+3]+=a*xv.w;
        } }
      float* op = h1 + (size_t)(base+n)*192 + h*64 + c0a;
      #pragma unroll
      for(int qq=0;qq<2;qq++){
        const float4 bv=*(const float4*)(bias + h*64 + c0a + qq*4);
        float4 r; r.x=elu_(acc[qq*4+0]+bv.x); r.y=elu_(acc[qq*4+1]+bv.y);
                  r.z=elu_(acc[qq*4+2]+bv.z); r.w=elu_(acc[qq*4+3]+bv.w);
        *(float4*)(op + qq*4)=r;
      }
    }
    __syncthreads();
  }
}

__global__ __launch_bounds__(512,4) void gat2_k(
    const float* __restrict__ h1, const int* __restrict__ ei,
    const float* __restrict__ ea, const float* __restrict__ Wl,
    const float* __restrict__ bl, const float* __restrict__ Wr,
    const float* __restrict__ br, const float* __restrict__ We,
    const float* __restrict__ att, const float* __restrict__ bias,
    const float* __restrict__ Wih, const float* __restrict__ bih,
    const float* __restrict__ bhh, float* __restrict__ xproj)
{
  const int g = blockIdx.x, tid = threadIdx.x;
  const int base = g*NPG;

  __shared__ __align__(16) float s_hx[NPG*36];
  __shared__ __align__(16) float s_xl[NPG*64];
  __shared__ __align__(16) float s_xr[NPG*64];
  __shared__ __align__(16) float s_W[2*32*64];   // also reused as s_out (64x64)
  __shared__ __align__(16) float s_We[16*64];
  __shared__ __align__(16) float s_att[64];
  __shared__ __align__(16) float s_la[NPG*EFD];
  __shared__ float s_sc[576];
  __shared__ float s_pool[64];
  __shared__ int   s_edge[EPG];
  __shared__ int   s_entry[EPG];
  __shared__ int   s_off[65];
  __shared__ int   s_deg[64];
  float* s_out = s_W;

  build_csr_la(tid, g, ei, ea, s_edge, s_entry, s_off, s_deg, s_la);

  // GEMM: xl/xr = h1 @ Wl2/Wr2 + b  (64x192 @ 192x64, 6 K-chunks of 32)
  const int cg=tid&15, ng=tid>>4, n0=ng*2, gc0=cg*4;
  float accl[2][4], accr[2][4];
  { const float4 blv=*(const float4*)(bl + gc0);
    const float4 brv=*(const float4*)(br + gc0);
    #pragma unroll
    for(int i=0;i<2;i++){
      accl[i][0]=blv.x; accl[i][1]=blv.y; accl[i][2]=blv.z; accl[i][3]=blv.w;
      accr[i][0]=brv.x; accr[i][1]=brv.y; accr[i][2]=brv.z; accr[i][3]=brv.w; } }
  for(int kc=0;kc<6;kc++){
    { int n=tid>>3, kq=tid&7;
      *(float4*)(s_hx + n*36 + kq*4) = *(const float4*)(h1 + (size_t)(base+n)*192 + kc*32 + kq*4); }
    { int k=tid>>4, cc=(tid&15)*4;
      *(float4*)(s_W + k*64 + cc)        = *(const float4*)(Wl + (size_t)(kc*32+k)*64 + cc);
      *(float4*)(s_W + 2048 + k*64 + cc) = *(const float4*)(Wr + (size_t)(kc*32+k)*64 + cc); }
    __syncthreads();
    #pragma unroll
    for(int kq=0;kq<8;kq++){
      float xs0[4], xs1[4];
      { float4 v=*(const float4*)(s_hx + n0*36 + kq*4);     xs0[0]=v.x;xs0[1]=v.y;xs0[2]=v.z;xs0[3]=v.w; }
      { float4 v=*(const float4*)(s_hx + (n0+1)*36 + kq*4); xs1[0]=v.x;xs1[1]=v.y;xs1[2]=v.z;xs1[3]=v.w; }
      #pragma unroll
      for(int f=0;f<4;f++){
        const float4 wl=*(const float4*)(s_W + (kq*4+f)*64 + gc0);
        const float4 wr=*(const float4*)(s_W + 2048 + (kq*4+f)*64 + gc0);
        accl[0][0]+=xs0[f]*wl.x; accl[0][1]+=xs0[f]*wl.y; accl[0][2]+=xs0[f]*wl.z; accl[0][3]+=xs0[f]*wl.w;
        accl[1][0]+=xs1[f]*wl.x; accl[1][1]+=xs1[f]*wl.y; accl[1][2]+=xs1[f]*wl.z; accl[1][3]+=xs1[f]*wl.w;
        accr[0][0]+=xs0[f]*wr.x; accr[0][1]+=xs0[f]*wr.y; accr[0][2]+=xs0[f]*wr.z; accr[0][3]+=xs0[f]*wr.w;
        accr[1][0]+=xs1[f]*wr.x; accr[1][1]+=xs1[f]*wr.y; accr[1][2]+=xs1[f]*wr.z; accr[1][3]+=xs1[f]*wr.w;
      }
    }
    __syncthreads();
  }
  // write xl/xr (swizzled) and stage We2/att2
  #pragma unroll
  for(int i=0;i<2;i++){
    const int n=n0+i, sq=((cg^(n&15))<<2);
    float4 vl; vl.x=accl[i][0]; vl.y=accl[i][1]; vl.z=accl[i][2]; vl.w=accl[i][3];
    float4 vr; vr.x=accr[i][0]; vr.y=accr[i][1]; vr.z=accr[i][2]; vr.w=accr[i][3];
    *(float4*)(s_xl + n*64 + sq)=vl;
    *(float4*)(s_xr + n*64 + sq)=vr;
  }
  if(tid<256){ int f=tid>>4, cc=(tid&15)*4;
    *(float4*)(s_We + f*64 + cc) = *(const float4*)(We + (size_t)f*64 + cc); }
  if(tid<16) *(float4*)(s_att + tid*4) = *(const float4*)(att + tid*4);
  __syncthreads();

  scores_softmax(tid, g, ea, s_entry, s_off, s_la, s_We, s_att, s_xl, s_xr, s_sc);

  // aggregate + bias + ELU into s_out (aliases s_W; GEMM done)
  { const int n=tid>>3, c0a=(tid&7)*8;
    float acc[8]={0.f,0.f,0.f,0.f,0.f,0.f,0.f,0.f};
    const int b=s_off[n], e=s_off[n+1];
    for(int p=b;p<e;p++){
      const int en=s_entry[p], src=en&63;
      const float a=s_sc[p];
      #pragma unroll
      for(int qq=0;qq<2;qq++){
        const int cq=(c0a>>2)+qq;
        const float4 xv=*(const float4*)(s_xl + src*64 + ((cq^(src&15))<<2));
        acc[qq*4+0]+=a*xv.x; acc[qq*4+1]+=a*xv.y; acc[qq*4+2]+=a*xv.z; acc[qq*4+3]+=a*xv.w;
      }
    }
    { const float a=s_sc[EPG+n];
      #pragma unroll
      for(int qq=0;qq<2;qq++){
        const int cq=(c0a>>2)+qq;
        const float4 xv=*(const float4*)(s_xl + n*64 + ((cq^(n&15))<<2));
        acc[qq*4+0]+=a*xv.x; acc[qq*4+1]+=a*xv.y; acc[qq*4+2]+=a*xv.z; acc[qq*4+3]+=a*xv.w;
      } }
    #pragma unroll
    for(int qq=0;qq<2;qq++){
      const float4 bv=*(const float4*)(bias + c0a + qq*4);
      float4 r; r.x=elu_(acc[qq*4+0]+bv.x); r.y=elu_(acc[qq*4+1]+bv.y);
                r.z=elu_(acc[qq*4+2]+bv.z); r.w=elu_(acc[qq*4+3]+bv.w);
      *(float4*)(s_out + n*64 + c0a + qq*4)=r;
    }
  }
  __syncthreads();
  // mean-pool over the 64 nodes
  if(tid<64){ float s=0.f;
    #pragma unroll 8
    for(int n2=0;n2<64;n2++) s += s_out[n2*64+tid];
    s_pool[tid]=s*(1.f/64.f); }
  __syncthreads();
  // LSTM input projection for this timestep: xproj[g][r] = bih[r]+bhh[r]+Wih[r]·pooled
  if(tid<256){
    float a=bih[tid]+bhh[tid];
    #pragma unroll
    for(int kq=0;kq<16;kq++){
      const float4 w=*(const float4*)(Wih + (size_t)tid*64 + kq*4);
      a += w.x*s_pool[kq*4+0] + w.y*s_pool[kq*4+1] + w.z*s_pool[kq*4+2] + w.w*s_pool[kq*4+3];
    }
    xproj[(size_t)g*256 + tid]=a;
  }
}

// LSTM: 256 threads, thread (l,q) = (tid>>2, tid&3): rows {m*64+l} m=0..3, k-quarter q.
// Per step: 64 FMA -> DPP quad butterfly (VALU, not LDS pipe) -> redundant gates on
// all 4 quad lanes (no divergence) -> double-buffered s_h, ONE barrier per step.
__global__ __launch_bounds__(256,1) void lstm_k(
    const float* __restrict__ xproj, const float* __restrict__ Whh,
    const float* __restrict__ W1, const float* __restrict__ b1,
    const float* __restrict__ W2, const float* __restrict__ b2,
    float* __restrict__ out)
{
  const int tid=threadIdx.x, l=tid>>2, q=tid&3;
  __shared__ __align__(16) float s_h[2][64];
  __shared__ float s_y[32];
  float w[4][16];
  #pragma unroll
  for(int m=0;m<4;m++){
    const float* wp = Whh + (size_t)(m*64+l)*64 + q*16;
    #pragma unroll
    for(int j=0;j<4;j++){
      const float4 v=*(const float4*)(wp + j*4);
      w[m][j*4]=v.x; w[m][j*4+1]=v.y; w[m][j*4+2]=v.z; w[m][j*4+3]=v.w;
    }
  }
  float c=0.f;
  float xp0=xproj[l], xp1=xproj[64+l], xp2=xproj[128+l], xp3=xproj[192+l];
  if(tid<64){ s_h[0][tid]=0.f; s_h[1][tid]=0.f; }
  __syncthreads();
  int cur=0;
  for(int t=0;t<1024;t++){
    float hb[16];
    #pragma unroll
    for(int j=0;j<4;j++){
      const float4 v=*(const float4*)(&s_h[cur][q*16 + j*4]);
      hb[j*4]=v.x; hb[j*4+1]=v.y; hb[j*4+2]=v.z; hb[j*4+3]=v.w;
    }
    float a0=0.f,a1=0.f,a2=0.f,a3=0.f;
    #pragma unroll
    for(int k=0;k<16;k++){
      a0+=w[0][k]*hb[k]; a1+=w[1][k]*hb[k]; a2+=w[2][k]*hb[k]; a3+=w[3][k]*hb[k];
    }
    // prefetch next timestep's xproj while the butterfly/gates run
    float xn0=0.f,xn1=0.f,xn2=0.f,xn3=0.f;
    if(t<1023){
      const float* xpp = xproj + (size_t)(t+1)*256;
      xn0=xpp[l]; xn1=xpp[64+l]; xn2=xpp[128+l]; xn3=xpp[192+l];
    }
    a0=quad_add(a0); a1=quad_add(a1); a2=quad_add(a2); a3=quad_add(a3);
    const float gi=a0+xp0, gf=a1+xp1, gg=a2+xp2, go=a3+xp3;
    c = sig_(gf)*c + sig_(gi)*tanhf_(gg);
    const float hn = sig_(go)*tanhf_(c);
    if(q==0) s_h[cur^1][l]=hn;
    xp0=xn0; xp1=xn1; xp2=xn2; xp3=xn3;
    cur^=1;
    __syncthreads();
  }
  // MLP head: relu(h@W1+b1)@W2+b2  (final h is in s_h[cur])
  if(tid<32){
    float a=b1[tid];
    #pragma unroll 8
    for(int k=0;k<64;k++) a += s_h[cur][k]*W1[k*32+tid];
    s_y[tid]=fmaxf(a,0.f);
  }
  __syncthreads();
  if(tid==0){
    float a=b2[0];
    #pragma unroll
    for(int j=0;j<32;j++) a += s_y[j]*W2[j];
    out[0]=a;
  }
}

extern "C" void kernel_launch(void* const* d_in, const int* in_sizes, int n_in,
                              void* d_out, int out_size, void* d_ws, size_t ws_size,
                              hipStream_t stream) {
  (void)in_sizes; (void)n_in; (void)out_size; (void)ws_size;
  const float* x    = (const float*)d_in[0];
  const int*   ei   = (const int*)d_in[1];
  const float* ea   = (const float*)d_in[2];
  const float* Wl1  = (const float*)d_in[4];
  const float* bl1  = (const float*)d_in[5];
  const float* Wr1  = (const float*)d_in[6];
  const float* br1  = (const float*)d_in[7];
  const float* We1  = (const float*)d_in[8];
  const float* att1 = (const float*)d_in[9];
  const float* bias1= (const float*)d_in[10];
  const float* Wl2  = (const float*)d_in[11];
  const float* bl2  = (const float*)d_in[12];
  const float* Wr2  = (const float*)d_in[13];
  const float* br2  = (const float*)d_in[14];
  const float* We2  = (const float*)d_in[15];
  const float* att2 = (const float*)d_in[16];
  const float* bias2= (const float*)d_in[17];
  const float* Wih  = (const float*)d_in[18];
  const float* Whh  = (const float*)d_in[19];
  const float* bih  = (const float*)d_in[20];
  const float* bhh  = (const float*)d_in[21];
  const float* W1   = (const float*)d_in[22];
  const float* b1   = (const float*)d_in[23];
  const float* W2   = (const float*)d_in[24];
  const float* b2   = (const float*)d_in[25];

  float* h1w = (float*)d_ws;                                  // 65536*192*4 = 50331648 B
  float* xpw = (float*)((char*)d_ws + (size_t)50331648);      // 1024*256*4  = 1048576 B
  float* outp = (float*)d_out;

  gat1_k<<<dim3(SGR), dim3(512), 0, stream>>>(x, ei, ea, Wl1, bl1, Wr1, br1, We1, att1, bias1, h1w);
  gat2_k<<<dim3(SGR), dim3(512), 0, stream>>>(h1w, ei, ea, Wl2, bl2, Wr2, br2, We2, att2, bias2,
                                              Wih, bih, bhh, xpw);
  lstm_k<<<dim3(1), dim3(256), 0, stream>>>(xpw, Whh, W1, b1, W2, b2, outp);
}

// Round 3
// 819.758 us; speedup vs baseline: 1.2411x; 1.0932x over previous
//
#include <hip/hip_runtime.h>

#define ETOT 524288
#define SGR  1024
#define NPG  64
#define EPG  512
#define NFD  32
#define EFD  16
#define HCD  64

__device__ __forceinline__ float elu_(float x){ return x>0.f ? x : (__expf(x)-1.f); }
__device__ __forceinline__ float sig_(float x){ return 1.f/(1.f+__expf(-x)); }
__device__ __forceinline__ float tanhf_(float x){ float e=__expf(2.f*x); return 1.f-2.f/(e+1.f); }
__device__ __forceinline__ float lrelu_(float x){ return x>0.f ? x : 0.2f*x; }

// sum over the 4 lanes of a quad, result in all 4 lanes — VALU DPP, no LDS pipe
__device__ __forceinline__ float quad_add(float v){
  int t = __builtin_amdgcn_update_dpp(0, __float_as_int(v), 0xB1, 0xF, 0xF, true); // [1,0,3,2]
  v += __int_as_float(t);
  t = __builtin_amdgcn_update_dpp(0, __float_as_int(v), 0x4E, 0xF, 0xF, true);     // [2,3,0,1]
  return v + __int_as_float(t);
}

// Deterministic CSR build + per-dst mean edge_attr (self-loop fill).
// Called by all 512 threads; contains barriers.
__device__ void build_csr_la(int tid, int g, const int* ei, const float* ea,
                             int* s_edge, int* s_entry, int* s_off, int* s_deg,
                             float* s_la)
{
  const int base = g*NPG;
  const int* srcp = ei + (size_t)g*EPG;
  const int* dstp = ei + (size_t)ETOT + (size_t)g*EPG;
  for(int e=tid;e<EPG;e+=512)
    s_edge[e] = (srcp[e]-base) | ((dstp[e]-base)<<6);
  __syncthreads();
  if(tid<64){ int d=0;
    #pragma unroll 8
    for(int e=0;e<EPG;e++) d += (((s_edge[e]>>6)&63)==tid);
    s_deg[tid]=d; }
  __syncthreads();
  if(tid==0){ int a=0;
    for(int i=0;i<64;i++){ s_off[i]=a; a+=s_deg[i]; }
    s_off[64]=a; }
  __syncthreads();
  if(tid<64){ int pos=s_off[tid];
    for(int e=0;e<EPG;e++){ int en=s_edge[e];
      if(((en>>6)&63)==tid) s_entry[pos++] = (en&63) | (tid<<6) | (e<<12); } }
  __syncthreads();
  if(tid<256){ int n=tid>>2, f0=(tid&3)*4;
    float a0=0,a1=0,a2=0,a3=0;
    const int b=s_off[n], en=s_off[n+1];
    for(int p=b;p<en;p++){ int eid=s_entry[p]>>12;
      const float4 v = *(const float4*)(ea + ((size_t)g*EPG+(size_t)eid)*EFD + f0);
      a0+=v.x; a1+=v.y; a2+=v.z; a3+=v.w; }
    float inv = 1.f/fmaxf((float)(en-b),1.f);
    float4 r; r.x=a0*inv; r.y=a1*inv; r.z=a2*inv; r.w=a3*inv;
    *(float4*)(s_la + n*EFD + f0) = r; }
  __syncthreads();
}

// scores (576 = 512 edges + 64 self loops) + per-dst softmax; alpha left in s_sc.
__device__ void scores_softmax(int tid, int g, const float* ea,
   const int* s_entry, const int* s_off, const float* s_la,
   const float* s_We, const float* s_att, const float* s_xl, const float* s_xr,
   float* s_sc)
{
  for(int p=tid;p<576;p+=512){
    int src,dst; float eav[16];
    if(p<EPG){
      int en=s_entry[p]; src=en&63; dst=(en>>6)&63; int eid=en>>12;
      const float* epp = ea + ((size_t)g*EPG + (size_t)eid)*EFD;
      float4 v0=*(const float4*)(epp),   v1=*(const float4*)(epp+4);
      float4 v2=*(const float4*)(epp+8), v3=*(const float4*)(epp+12);
      eav[0]=v0.x;eav[1]=v0.y;eav[2]=v0.z;eav[3]=v0.w;
      eav[4]=v1.x;eav[5]=v1.y;eav[6]=v1.z;eav[7]=v1.w;
      eav[8]=v2.x;eav[9]=v2.y;eav[10]=v2.z;eav[11]=v2.w;
      eav[12]=v3.x;eav[13]=v3.y;eav[14]=v3.z;eav[15]=v3.w;
    } else {
      int n=p-EPG; src=n; dst=n;
      const float* epp = s_la + n*EFD;
      float4 v0=*(const float4*)(epp),   v1=*(const float4*)(epp+4);
      float4 v2=*(const float4*)(epp+8), v3=*(const float4*)(epp+12);
      eav[0]=v0.x;eav[1]=v0.y;eav[2]=v0.z;eav[3]=v0.w;
      eav[4]=v1.x;eav[5]=v1.y;eav[6]=v1.z;eav[7]=v1.w;
      eav[8]=v2.x;eav[9]=v2.y;eav[10]=v2.z;eav[11]=v2.w;
      eav[12]=v3.x;eav[13]=v3.y;eav[14]=v3.z;eav[15]=v3.w;
    }
    float score=0.f;
    #pragma unroll 4
    for(int cq=0;cq<16;cq++){
      float e0=0.f,e1=0.f,e2=0.f,e3=0.f;
      #pragma unroll
      for(int f=0;f<16;f++){
        const float4 wv=*(const float4*)(s_We + f*64 + cq*4);
        e0+=eav[f]*wv.x; e1+=eav[f]*wv.y; e2+=eav[f]*wv.z; e3+=eav[f]*wv.w;
      }
      const float4 xlv=*(const float4*)(s_xl + src*64 + ((cq^(src&15))<<2));
      const float4 xrv=*(const float4*)(s_xr + dst*64 + ((cq^(dst&15))<<2));
      const float4 av =*(const float4*)(s_att + cq*4);
      float m0=lrelu_(xlv.x+xrv.x+e0), m1=lrelu_(xlv.y+xrv.y+e1);
      float m2=lrelu_(xlv.z+xrv.z+e2), m3=lrelu_(xlv.w+xrv.w+e3);
      score += m0*av.x+m1*av.y+m2*av.z+m3*av.w;
    }
    s_sc[p]=score;
  }
  __syncthreads();
  if(tid<64){
    const int b=s_off[tid], e=s_off[tid+1];
    float mx=s_sc[EPG+tid];
    for(int p=b;p<e;p++) mx=fmaxf(mx,s_sc[p]);
    float v=__expf(s_sc[EPG+tid]-mx); float den=v; s_sc[EPG+tid]=v;
    for(int p=b;p<e;p++){ float w=__expf(s_sc[p]-mx); s_sc[p]=w; den+=w; }
    const float inv=1.f/(den+1e-16f);
    s_sc[EPG+tid]*=inv;
    for(int p=b;p<e;p++) s_sc[p]*=inv;
  }
  __syncthreads();
}

__global__ __launch_bounds__(512,4) void gat1_k(
    const float* __restrict__ x, const int* __restrict__ ei,
    const float* __restrict__ ea, const float* __restrict__ Wl,
    const float* __restrict__ bl, const float* __restrict__ Wr,
    const float* __restrict__ br, const float* __restrict__ We,
    const float* __restrict__ att, const float* __restrict__ bias,
    float* __restrict__ h1)
{
  const int g = blockIdx.x, tid = threadIdx.x;
  const int base = g*NPG;

  __shared__ __align__(16) float s_x[NPG*36];
  __shared__ __align__(16) float s_xl[NPG*64];
  __shared__ __align__(16) float s_xr[NPG*64];
  __shared__ __align__(16) float s_W[2*32*64];
  __shared__ __align__(16) float s_We[16*64];
  __shared__ __align__(16) float s_att[64];
  __shared__ __align__(16) float s_la[NPG*EFD];
  __shared__ float s_sc[576];
  __shared__ int   s_edge[EPG];
  __shared__ int   s_entry[EPG];
  __shared__ int   s_off[65];
  __shared__ int   s_deg[64];

  // stage x tile [64][32] (padded stride 36)
  { int n=tid>>3, kq=tid&7;
    float4 v = *(const float4*)(x + (size_t)(base+n)*NFD + kq*4);
    *(float4*)(s_x + n*36 + kq*4) = v; }

  build_csr_la(tid, g, ei, ea, s_edge, s_entry, s_off, s_deg, s_la);

  for(int h=0;h<3;h++){
    // stage weight slices for this head
    { int k=tid>>4, c0=(tid&15)*4;
      *(float4*)(s_W + k*64 + c0)        = *(const float4*)(Wl + (size_t)k*192 + h*64 + c0);
      *(float4*)(s_W + 2048 + k*64 + c0) = *(const float4*)(Wr + (size_t)k*192 + h*64 + c0); }
    if(tid<256){ int f=tid>>4, c0=(tid&15)*4;
      *(float4*)(s_We + f*64 + c0) = *(const float4*)(We + (size_t)f*192 + h*64 + c0); }
    if(tid<16) *(float4*)(s_att + tid*4) = *(const float4*)(att + h*64 + tid*4);
    __syncthreads();

    // GEMM: xl = x@Wl_h + bl_h ; xr = x@Wr_h + br_h  (64x32 @ 32x64)
    { const int cg=tid&15, ng=tid>>4, n0=ng*2, c0=cg*4;
      const float4 blv=*(const float4*)(bl + h*64 + c0);
      const float4 brv=*(const float4*)(br + h*64 + c0);
      float accl[2][4]={{blv.x,blv.y,blv.z,blv.w},{blv.x,blv.y,blv.z,blv.w}};
      float accr[2][4]={{brv.x,brv.y,brv.z,brv.w},{brv.x,brv.y,brv.z,brv.w}};
      #pragma unroll
      for(int kq=0;kq<8;kq++){
        float xs0[4], xs1[4];
        { float4 v=*(const float4*)(s_x + n0*36 + kq*4);     xs0[0]=v.x;xs0[1]=v.y;xs0[2]=v.z;xs0[3]=v.w; }
        { float4 v=*(const float4*)(s_x + (n0+1)*36 + kq*4); xs1[0]=v.x;xs1[1]=v.y;xs1[2]=v.z;xs1[3]=v.w; }
        #pragma unroll
        for(int f=0;f<4;f++){
          const float4 wl=*(const float4*)(s_W + (kq*4+f)*64 + c0);
          const float4 wr=*(const float4*)(s_W + 2048 + (kq*4+f)*64 + c0);
          accl[0][0]+=xs0[f]*wl.x; accl[0][1]+=xs0[f]*wl.y; accl[0][2]+=xs0[f]*wl.z; accl[0][3]+=xs0[f]*wl.w;
          accl[1][0]+=xs1[f]*wl.x; accl[1][1]+=xs1[f]*wl.y; accl[1][2]+=xs1[f]*wl.z; accl[1][3]+=xs1[f]*wl.w;
          accr[0][0]+=xs0[f]*wr.x; accr[0][1]+=xs0[f]*wr.y; accr[0][2]+=xs0[f]*wr.z; accr[0][3]+=xs0[f]*wr.w;
          accr[1][0]+=xs1[f]*wr.x; accr[1][1]+=xs1[f]*wr.y; accr[1][2]+=xs1[f]*wr.z; accr[1][3]+=xs1[f]*wr.w;
        }
      }
      #pragma unroll
      for(int i=0;i<2;i++){
        const int n=n0+i, sq=((cg^(n&15))<<2);
        float4 vl; vl.x=accl[i][0]; vl.y=accl[i][1]; vl.z=accl[i][2]; vl.w=accl[i][3];
        float4 vr; vr.x=accr[i][0]; vr.y=accr[i][1]; vr.z=accr[i][2]; vr.w=accr[i][3];
        *(float4*)(s_xl + n*64 + sq)=vl;
        *(float4*)(s_xr + n*64 + sq)=vr;
      }
    }
    __syncthreads();

    scores_softmax(tid, g, ea, s_entry, s_off, s_la, s_We, s_att, s_xl, s_xr, s_sc);

    // aggregate alpha * xl[src] per (dst, 8-channel slice) + bias + ELU -> h1
    { const int n=tid>>3, c0a=(tid&7)*8;
      float acc[8]={0.f,0.f,0.f,0.f,0.f,0.f,0.f,0.f};
      const int b=s_off[n], e=s_off[n+1];
      for(int p=b;p<e;p++){
        const int en=s_entry[p], src=en&63;
        const float a=s_sc[p];
        #pragma unroll
        for(int qq=0;qq<2;qq++){
          const int cq=(c0a>>2)+qq;
          const float4 xv=*(const float4*)(s_xl + src*64 + ((cq^(src&15))<<2));
          acc[qq*4+0]+=a*xv.x; acc[qq*4+1]+=a*xv.y; acc[qq*4+2]+=a*xv.z; acc[qq*4+3]+=a*xv.w;
        }
      }
      { const float a=s_sc[EPG+n];
        #pragma unroll
        for(int qq=0;qq<2;qq++){
          const int cq=(c0a>>2)+qq;
          const float4 xv=*(const float4*)(s_xl + n*64 + ((cq^(n&15))<<2));
          acc[qq*4+0]+=a*xv.x; acc[qq*4+1]+=a*xv.y; acc[qq*4+2]+=a*xv.z; acc[qq*4+3]+=a*xv.w;
        } }
      float* op = h1 + (size_t)(base+n)*192 + h*64 + c0a;
      #pragma unroll
      for(int qq=0;qq<2;qq++){
        const float4 bv=*(const float4*)(bias + h*64 + c0a + qq*4);
        float4 r; r.x=elu_(acc[qq*4+0]+bv.x); r.y=elu_(acc[qq*4+1]+bv.y);
                  r.z=elu_(acc[qq*4+2]+bv.z); r.w=elu_(acc[qq*4+3]+bv.w);
        *(float4*)(op + qq*4)=r;
      }
    }
    __syncthreads();
  }
}

__global__ __launch_bounds__(512,4) void gat2_k(
    const float* __restrict__ h1, const int* __restrict__ ei,
    const float* __restrict__ ea, const float* __restrict__ Wl,
    const float* __restrict__ bl, const float* __restrict__ Wr,
    const float* __restrict__ br, const float* __restrict__ We,
    const float* __restrict__ att, const float* __restrict__ bias,
    const float* __restrict__ Wih, const float* __restrict__ bih,
    const float* __restrict__ bhh, float* __restrict__ xproj)
{
  const int g = blockIdx.x, tid = threadIdx.x;
  const int base = g*NPG;

  __shared__ __align__(16) float s_hx[NPG*36];
  __shared__ __align__(16) float s_xl[NPG*64];
  __shared__ __align__(16) float s_xr[NPG*64];
  __shared__ __align__(16) float s_W[2*32*64];   // also reused as s_out (64x64)
  __shared__ __align__(16) float s_We[16*64];
  __shared__ __align__(16) float s_att[64];
  __shared__ __align__(16) float s_la[NPG*EFD];
  __shared__ float s_sc[576];
  __shared__ float s_pool[64];
  __shared__ int   s_edge[EPG];
  __shared__ int   s_entry[EPG];
  __shared__ int   s_off[65];
  __shared__ int   s_deg[64];
  float* s_out = s_W;

  build_csr_la(tid, g, ei, ea, s_edge, s_entry, s_off, s_deg, s_la);

  // GEMM: xl/xr = h1 @ Wl2/Wr2 + b  (64x192 @ 192x64, 6 K-chunks of 32)
  const int cg=tid&15, ng=tid>>4, n0=ng*2, gc0=cg*4;
  float accl[2][4], accr[2][4];
  { const float4 blv=*(const float4*)(bl + gc0);
    const float4 brv=*(const float4*)(br + gc0);
    #pragma unroll
    for(int i=0;i<2;i++){
      accl[i][0]=blv.x; accl[i][1]=blv.y; accl[i][2]=blv.z; accl[i][3]=blv.w;
      accr[i][0]=brv.x; accr[i][1]=brv.y; accr[i][2]=brv.z; accr[i][3]=brv.w; } }
  for(int kc=0;kc<6;kc++){
    { int n=tid>>3, kq=tid&7;
      *(float4*)(s_hx + n*36 + kq*4) = *(const float4*)(h1 + (size_t)(base+n)*192 + kc*32 + kq*4); }
    { int k=tid>>4, cc=(tid&15)*4;
      *(float4*)(s_W + k*64 + cc)        = *(const float4*)(Wl + (size_t)(kc*32+k)*64 + cc);
      *(float4*)(s_W + 2048 + k*64 + cc) = *(const float4*)(Wr + (size_t)(kc*32+k)*64 + cc); }
    __syncthreads();
    #pragma unroll
    for(int kq=0;kq<8;kq++){
      float xs0[4], xs1[4];
      { float4 v=*(const float4*)(s_hx + n0*36 + kq*4);     xs0[0]=v.x;xs0[1]=v.y;xs0[2]=v.z;xs0[3]=v.w; }
      { float4 v=*(const float4*)(s_hx + (n0+1)*36 + kq*4); xs1[0]=v.x;xs1[1]=v.y;xs1[2]=v.z;xs1[3]=v.w; }
      #pragma unroll
      for(int f=0;f<4;f++){
        const float4 wl=*(const float4*)(s_W + (kq*4+f)*64 + gc0);
        const float4 wr=*(const float4*)(s_W + 2048 + (kq*4+f)*64 + gc0);
        accl[0][0]+=xs0[f]*wl.x; accl[0][1]+=xs0[f]*wl.y; accl[0][2]+=xs0[f]*wl.z; accl[0][3]+=xs0[f]*wl.w;
        accl[1][0]+=xs1[f]*wl.x; accl[1][1]+=xs1[f]*wl.y; accl[1][2]+=xs1[f]*wl.z; accl[1][3]+=xs1[f]*wl.w;
        accr[0][0]+=xs0[f]*wr.x; accr[0][1]+=xs0[f]*wr.y; accr[0][2]+=xs0[f]*wr.z; accr[0][3]+=xs0[f]*wr.w;
        accr[1][0]+=xs1[f]*wr.x; accr[1][1]+=xs1[f]*wr.y; accr[1][2]+=xs1[f]*wr.z; accr[1][3]+=xs1[f]*wr.w;
      }
    }
    __syncthreads();
  }
  // write xl/xr (swizzled) and stage We2/att2
  #pragma unroll
  for(int i=0;i<2;i++){
    const int n=n0+i, sq=((cg^(n&15))<<2);
    float4 vl; vl.x=accl[i][0]; vl.y=accl[i][1]; vl.z=accl[i][2]; vl.w=accl[i][3];
    float4 vr; vr.x=accr[i][0]; vr.y=accr[i][1]; vr.z=accr[i][2]; vr.w=accr[i][3];
    *(float4*)(s_xl + n*64 + sq)=vl;
    *(float4*)(s_xr + n*64 + sq)=vr;
  }
  if(tid<256){ int f=tid>>4, cc=(tid&15)*4;
    *(float4*)(s_We + f*64 + cc) = *(const float4*)(We + (size_t)f*64 + cc); }
  if(tid<16) *(float4*)(s_att + tid*4) = *(const float4*)(att + tid*4);
  __syncthreads();

  scores_softmax(tid, g, ea, s_entry, s_off, s_la, s_We, s_att, s_xl, s_xr, s_sc);

  // aggregate + bias + ELU into s_out (aliases s_W; GEMM done)
  { const int n=tid>>3, c0a=(tid&7)*8;
    float acc[8]={0.f,0.f,0.f,0.f,0.f,0.f,0.f,0.f};
    const int b=s_off[n], e=s_off[n+1];
    for(int p=b;p<e;p++){
      const int en=s_entry[p], src=en&63;
      const float a=s_sc[p];
      #pragma unroll
      for(int qq=0;qq<2;qq++){
        const int cq=(c0a>>2)+qq;
        const float4 xv=*(const float4*)(s_xl + src*64 + ((cq^(src&15))<<2));
        acc[qq*4+0]+=a*xv.x; acc[qq*4+1]+=a*xv.y; acc[qq*4+2]+=a*xv.z; acc[qq*4+3]+=a*xv.w;
      }
    }
    { const float a=s_sc[EPG+n];
      #pragma unroll
      for(int qq=0;qq<2;qq++){
        const int cq=(c0a>>2)+qq;
        const float4 xv=*(const float4*)(s_xl + n*64 + ((cq^(n&15))<<2));
        acc[qq*4+0]+=a*xv.x; acc[qq*4+1]+=a*xv.y; acc[qq*4+2]+=a*xv.z; acc[qq*4+3]+=a*xv.w;
      } }
    #pragma unroll
    for(int qq=0;qq<2;qq++){
      const float4 bv=*(const float4*)(bias + c0a + qq*4);
      float4 r; r.x=elu_(acc[qq*4+0]+bv.x); r.y=elu_(acc[qq*4+1]+bv.y);
                r.z=elu_(acc[qq*4+2]+bv.z); r.w=elu_(acc[qq*4+3]+bv.w);
      *(float4*)(s_out + n*64 + c0a + qq*4)=r;
    }
  }
  __syncthreads();
  // mean-pool over the 64 nodes
  if(tid<64){ float s=0.f;
    #pragma unroll 8
    for(int n2=0;n2<64;n2++) s += s_out[n2*64+tid];
    s_pool[tid]=s*(1.f/64.f); }
  __syncthreads();
  // LSTM input projection for this timestep: xproj[g][r] = bih[r]+bhh[r]+Wih[r]·pooled
  if(tid<256){
    float a=bih[tid]+bhh[tid];
    #pragma unroll
    for(int kq=0;kq<16;kq++){
      const float4 w=*(const float4*)(Wih + (size_t)tid*64 + kq*4);
      a += w.x*s_pool[kq*4+0] + w.y*s_pool[kq*4+1] + w.z*s_pool[kq*4+2] + w.w*s_pool[kq*4+3];
    }
    xproj[(size_t)g*256 + tid]=a;
  }
}

// LSTM: 256 threads, thread (l,q) = (tid>>2, tid&3): rows {m*64+l} m=0..3, k-quarter q.
// Weights are PINNED in VGPRs via asm laundering (r2 post-mortem: compiler sank the
// Whh loads into the loop at VGPR_Count=48 -> ~650 cyc/step L2-reload stall).
__global__ __launch_bounds__(256,1) void lstm_k(
    const float* __restrict__ xproj, const float* __restrict__ Whh,
    const float* __restrict__ W1, const float* __restrict__ b1,
    const float* __restrict__ W2, const float* __restrict__ b2,
    float* __restrict__ out)
{
  const int tid=threadIdx.x, l=tid>>2, q=tid&3;
  __shared__ __align__(16) float s_h[2][64];
  __shared__ float s_y[32];
  float w[64];
  #pragma unroll
  for(int m=0;m<4;m++){
    const float* wp = Whh + (size_t)(m*64+l)*64 + q*16;
    #pragma unroll
    for(int j=0;j<4;j++){
      const float4 v=*(const float4*)(wp + j*4);
      w[m*16+j*4+0]=v.x; w[m*16+j*4+1]=v.y; w[m*16+j*4+2]=v.z; w[m*16+j*4+3]=v.w;
    }
  }
  // launder: value now "comes from" the asm -> compiler cannot re-load from memory
  #pragma unroll
  for(int i=0;i<64;i++) asm volatile("" : "+v"(w[i]));

  float c=0.f;
  float xp0=xproj[l], xp1=xproj[64+l], xp2=xproj[128+l], xp3=xproj[192+l];
  if(tid<64){ s_h[0][tid]=0.f; s_h[1][tid]=0.f; }
  __syncthreads();
  int cur=0;
  for(int t=0;t<1024;t++){
    float hb[16];
    #pragma unroll
    for(int j=0;j<4;j++){
      const float4 v=*(const float4*)(&s_h[cur][q*16 + j*4]);
      hb[j*4]=v.x; hb[j*4+1]=v.y; hb[j*4+2]=v.z; hb[j*4+3]=v.w;
    }
    // prefetch next timestep's xproj while this step computes
    float xn0=0.f,xn1=0.f,xn2=0.f,xn3=0.f;
    if(t<1023){
      const float* xpp = xproj + (size_t)(t+1)*256;
      xn0=xpp[l]; xn1=xpp[64+l]; xn2=xpp[128+l]; xn3=xpp[192+l];
    }
    // two 8-deep partial chains per gate (latency ~40 vs 64 cyc)
    float p0a=0.f,p0b=0.f,p1a=0.f,p1b=0.f,p2a=0.f,p2b=0.f,p3a=0.f,p3b=0.f;
    #pragma unroll
    for(int k=0;k<8;k++){
      p0a+=w[k]*hb[k];    p1a+=w[16+k]*hb[k];
      p2a+=w[32+k]*hb[k]; p3a+=w[48+k]*hb[k];
    }
    #pragma unroll
    for(int k=8;k<16;k++){
      p0b+=w[k]*hb[k];    p1b+=w[16+k]*hb[k];
      p2b+=w[32+k]*hb[k]; p3b+=w[48+k]*hb[k];
    }
    float a0=quad_add(p0a+p0b), a1=quad_add(p1a+p1b);
    float a2=quad_add(p2a+p2b), a3=quad_add(p3a+p3b);
    const float gi=a0+xp0, gf=a1+xp1, gg=a2+xp2, go=a3+xp3;
    c = sig_(gf)*c + sig_(gi)*tanhf_(gg);
    const float hn = sig_(go)*tanhf_(c);
    if(q==0) s_h[cur^1][l]=hn;
    xp0=xn0; xp1=xn1; xp2=xn2; xp3=xn3;
    cur^=1;
    __syncthreads();
  }
  // MLP head: relu(h@W1+b1)@W2+b2  (final h is in s_h[cur])
  if(tid<32){
    float a=b1[tid];
    #pragma unroll 8
    for(int k=0;k<64;k++) a += s_h[cur][k]*W1[k*32+tid];
    s_y[tid]=fmaxf(a,0.f);
  }
  __syncthreads();
  if(tid==0){
    float a=b2[0];
    #pragma unroll
    for(int j=0;j<32;j++) a += s_y[j]*W2[j];
    out[0]=a;
  }
}

extern "C" void kernel_launch(void* const* d_in, const int* in_sizes, int n_in,
                              void* d_out, int out_size, void* d_ws, size_t ws_size,
                              hipStream_t stream) {
  (void)in_sizes; (void)n_in; (void)out_size; (void)ws_size;
  const float* x    = (const float*)d_in[0];
  const int*   ei   = (const int*)d_in[1];
  const float* ea   = (const float*)d_in[2];
  const float* Wl1  = (const float*)d_in[4];
  const float* bl1  = (const float*)d_in[5];
  const float* Wr1  = (const float*)d_in[6];
  const float* br1  = (const float*)d_in[7];
  const float* We1  = (const float*)d_in[8];
  const float* att1 = (const float*)d_in[9];
  const float* bias1= (const float*)d_in[10];
  const float* Wl2  = (const float*)d_in[11];
  const float* bl2  = (const float*)d_in[12];
  const float* Wr2  = (const float*)d_in[13];
  const float* br2  = (const float*)d_in[14];
  const float* We2  = (const float*)d_in[15];
  const float* att2 = (const float*)d_in[16];
  const float* bias2= (const float*)d_in[17];
  const float* Wih  = (const float*)d_in[18];
  const float* Whh  = (const float*)d_in[19];
  const float* bih  = (const float*)d_in[20];
  const float* bhh  = (const float*)d_in[21];
  const float* W1   = (const float*)d_in[22];
  const float* b1   = (const float*)d_in[23];
  const float* W2   = (const float*)d_in[24];
  const float* b2   = (const float*)d_in[25];

  float* h1w = (float*)d_ws;                                  // 65536*192*4 = 50331648 B
  float* xpw = (float*)((char*)d_ws + (size_t)50331648);      // 1024*256*4  = 1048576 B
  float* outp = (float*)d_out;

  gat1_k<<<dim3(SGR), dim3(512), 0, stream>>>(x, ei, ea, Wl1, bl1, Wr1, br1, We1, att1, bias1, h1w);
  gat2_k<<<dim3(SGR), dim3(512), 0, stream>>>(h1w, ei, ea, Wl2, bl2, Wr2, br2, We2, att2, bias2,
                                              Wih, bih, bhh, xpw);
  lstm_k<<<dim3(1), dim3(256), 0, stream>>>(xpw, Whh, W1, b1, W2, b2, outp);
}